// Round 12
// baseline (481.609 us; speedup 1.0000x reference)
//
#include <hip/hip_runtime.h>

#define W 64
#define D 256
#define NH 8

typedef unsigned short u16;
typedef unsigned int u32;
typedef __attribute__((ext_vector_type(8))) short bf16x8;
typedef __attribute__((ext_vector_type(4))) float f32x4;

__device__ __forceinline__ u16 f2bf(float f) {
    union { float f; unsigned u; } v; v.f = f;
    unsigned r = v.u + 0x7fffu + ((v.u >> 16) & 1u);
    return (u16)(r >> 16);
}

// packed f32x2 -> bf16x2, plain C (RNE); compiler schedules/packs itself.
__device__ __forceinline__ u32 pk2(float lo, float hi) {
    return (u32)f2bf(lo) | ((u32)f2bf(hi) << 16);
}

typedef union { u32 w[4]; bf16x8 f; } frag_u;

// fragment element j <- (a,b)[j>>2][j&3]
__device__ __forceinline__ bf16x8 pack8(f32x4 a, f32x4 b) {
    frag_u u;
    u.w[0] = pk2(a[0], a[1]);
    u.w[1] = pk2(a[2], a[3]);
    u.w[2] = pk2(b[0], b[1]);
    u.w[3] = pk2(b[2], b[3]);
    return u.f;
}

// ---------------- LDS layout (bytes) ----------------
// xs   : [64][264] u16  x bf16 staging; dead after QKV; aliased by attn_out 33792
// bias : [8][128] f32 rel-pos bias table                                     4096
// total 37888  (no transposer buffers: Q/K/V/P all stay in registers via
// the consistent-k-permutation trick: both MFMA operands carry the same
// channel bijection c(g,j)=16(j>>2)+4g+(j&3), so contraction is exact)
#define XS_ROW 264
#define OFF_BIAS 33792

__global__ __launch_bounds__(512, 4) void win_attn9(
    const float* __restrict__ x, const float* __restrict__ bqkv,
    const float* __restrict__ bproj, const float* __restrict__ relb,
    const u16* __restrict__ wqkvT, const u16* __restrict__ wprojT,
    float* __restrict__ out)
{
    __shared__ __align__(16) char smem[37888];

    const int tid  = threadIdx.x;
    const int lane = tid & 63;
    const int h    = tid >> 6;      // wave index == head
    const int l15  = lane & 15;
    const int g    = lane >> 4;
    const int w    = blockIdx.x;

    u16*   xs      = (u16*)smem;
    float* bias_ld = (float*)(smem + OFF_BIAS);

    const f32x4 z4 = {0.f, 0.f, 0.f, 0.f};

    // ---------- Phase 0: bias table + stage x window -> LDS bf16 ----------
    for (int i = tid; i < NH * 127; i += 512)
        bias_ld[(i / 127) * 128 + (i % 127)] = relb[i];

    const float* xw = x + (size_t)w * (W * D);
    #pragma unroll
    for (int i = 0; i < 8; ++i) {
        int e = i * 2048 + tid * 4;
        int row = e >> 8, col = e & 255;
        float4 v = *(const float4*)(xw + e);
        ushort4 b;
        b.x = f2bf(v.x); b.y = f2bf(v.y); b.z = f2bf(v.z); b.w = f2bf(v.w);
        *(ushort4*)(xs + row * XS_ROW + col) = b;
    }
    __syncthreads();

    // ---------- Phase 1: QKV, all fragments built in-register ----------
    // Q,K via swapped GEMM (M=channels, N=tokens): lane l15 = token,
    // regs (mt,r) = channel 16mt+4g+r -> pack8 gives k-perm c(g,j).
    bf16x8 qf[4], kf[4], vf[2][2];

    #pragma unroll
    for (int mat = 0; mat < 2; ++mat) {
        f32x4 acc[2][4];
        #pragma unroll
        for (int mt = 0; mt < 2; ++mt)
            #pragma unroll
            for (int nt = 0; nt < 4; ++nt)
                acc[mt][nt] = z4;

        const u16* w0 = wqkvT + (size_t)(mat * 256 + h * 32 + l15) * 256;
        const u16* w1 = w0 + 16 * 256;
        #pragma unroll
        for (int ks = 0; ks < 8; ++ks) {
            bf16x8 a0 = *(const bf16x8*)(w0 + ks * 32 + g * 8);
            bf16x8 a1 = *(const bf16x8*)(w1 + ks * 32 + g * 8);
            #pragma unroll
            for (int nt = 0; nt < 4; ++nt) {
                bf16x8 xb = *(const bf16x8*)(xs + (16 * nt + l15) * XS_ROW + ks * 32 + g * 8);
                acc[0][nt] = __builtin_amdgcn_mfma_f32_16x16x32_bf16(a0, xb, acc[0][nt], 0, 0, 0);
                acc[1][nt] = __builtin_amdgcn_mfma_f32_16x16x32_bf16(a1, xb, acc[1][nt], 0, 0, 0);
            }
        }
        // bias for channel 16mt+4g+r (per-lane, L1-hot; b_qkv)
        const float* bb = bqkv + mat * 256 + h * 32 + 4 * g;
        f32x4 b0v, b1v;
        #pragma unroll
        for (int r = 0; r < 4; ++r) { b0v[r] = bb[r]; b1v[r] = bb[16 + r]; }
        #pragma unroll
        for (int nt = 0; nt < 4; ++nt) {
            bf16x8 fr = pack8(acc[0][nt] + b0v, acc[1][nt] + b1v);
            if (mat == 0) qf[nt] = fr; else kf[nt] = fr;
        }
    }
    {
        // V via normal GEMM (M=tokens, N=channels): lane l15 = channel,
        // regs (mt,r) = token 16mt+4g+r -> vf[ks][cd] is the O^T A-frag.
        f32x4 acc[4][2];
        #pragma unroll
        for (int mt = 0; mt < 4; ++mt) { acc[mt][0] = z4; acc[mt][1] = z4; }

        const u16* w0 = wqkvT + (size_t)(512 + h * 32 + l15) * 256;
        const u16* w1 = w0 + 16 * 256;
        #pragma unroll
        for (int ks = 0; ks < 8; ++ks) {
            bf16x8 b0 = *(const bf16x8*)(w0 + ks * 32 + g * 8);
            bf16x8 b1 = *(const bf16x8*)(w1 + ks * 32 + g * 8);
            #pragma unroll
            for (int mt = 0; mt < 4; ++mt) {
                bf16x8 xa = *(const bf16x8*)(xs + (16 * mt + l15) * XS_ROW + ks * 32 + g * 8);
                acc[mt][0] = __builtin_amdgcn_mfma_f32_16x16x32_bf16(xa, b0, acc[mt][0], 0, 0, 0);
                acc[mt][1] = __builtin_amdgcn_mfma_f32_16x16x32_bf16(xa, b1, acc[mt][1], 0, 0, 0);
            }
        }
        const float bv0 = bqkv[512 + h * 32 + l15];
        const float bv1 = bqkv[512 + h * 32 + 16 + l15];
        const f32x4 bv0v = {bv0, bv0, bv0, bv0};
        const f32x4 bv1v = {bv1, bv1, bv1, bv1};
        #pragma unroll
        for (int ks = 0; ks < 2; ++ks) {
            vf[ks][0] = pack8(acc[2 * ks][0] + bv0v, acc[2 * ks + 1][0] + bv0v);
            vf[ks][1] = pack8(acc[2 * ks][1] + bv1v, acc[2 * ks + 1][1] + bv1v);
        }
    }
    __syncthreads();   // all xs reads done -> ao may alias xs

    // ---------- Phase 2: attention, fully in-register ----------
    const float scale = 0.17677669529663687f;   // 1/sqrt(32)
    u16* ao = xs;
    const float* bl_base = bias_ld + h * 128 + 63 + 4 * g;

    #pragma unroll
    for (int nt = 0; nt < 4; ++nt) {
        // S^T[k][q] for q-tile nt: lane l15 = q, regs (mtk,r) = k-token 16mtk+4g+r
        f32x4 st[4];
        #pragma unroll
        for (int mtk = 0; mtk < 4; ++mtk)
            st[mtk] = __builtin_amdgcn_mfma_f32_16x16x32_bf16(kf[mtk], qf[nt], z4, 0, 0, 0);

        const float* bl = bl_base - 16 * nt - l15;   // + (16mtk + r) in [0,126]
        f32x4 ev[4];
        float esum = 0.f;
        #pragma unroll
        for (int mtk = 0; mtk < 4; ++mtk)
            #pragma unroll
            for (int r = 0; r < 4; ++r) {
                float sv = st[mtk][r] * scale + bl[16 * mtk + r];
                float e = __expf(sv);
                ev[mtk][r] = e;
                esum += e;
            }
        esum += __shfl_xor(esum, 16, 64);
        esum += __shfl_xor(esum, 32, 64);
        const float inv = 1.0f / esum;
        #pragma unroll
        for (int mtk = 0; mtk < 4; ++mtk)
            #pragma unroll
            for (int r = 0; r < 4; ++r)
                ev[mtk][r] *= inv;

        bf16x8 pf0 = pack8(ev[0], ev[1]);   // P^T B-frag, k-half 0
        bf16x8 pf1 = pack8(ev[2], ev[3]);   // k-half 1

        #pragma unroll
        for (int cd = 0; cd < 2; ++cd) {
            f32x4 o = __builtin_amdgcn_mfma_f32_16x16x32_bf16(vf[0][cd], pf0, z4, 0, 0, 0);
            o = __builtin_amdgcn_mfma_f32_16x16x32_bf16(vf[1][cd], pf1, o, 0, 0, 0);
            // O^T: lane l15 = q-token, regs r = d 16cd+4g+r
            uint2 pkd;
            pkd.x = pk2(o[0], o[1]);
            pkd.y = pk2(o[2], o[3]);
            *(uint2*)(ao + (16 * nt + l15) * XS_ROW + h * 32 + 16 * cd + 4 * g) = pkd;
        }
    }
    __syncthreads();   // ao complete (cross-wave input to proj)

    // ---------- Phase 3: output projection (wave h -> cols h*32..+31) ----------
    f32x4 pacc[2][4];
    #pragma unroll
    for (int ct = 0; ct < 2; ++ct)
        #pragma unroll
        for (int rt = 0; rt < 4; ++rt)
            pacc[ct][rt] = z4;

    const u16* pp0 = wprojT + (size_t)(h * 32 + l15) * 256;
    const u16* pp1 = pp0 + 16 * 256;
    #pragma unroll
    for (int ks = 0; ks < 8; ++ks) {
        bf16x8 b0 = *(const bf16x8*)(pp0 + ks * 32 + g * 8);
        bf16x8 b1 = *(const bf16x8*)(pp1 + ks * 32 + g * 8);
        #pragma unroll
        for (int rt = 0; rt < 4; ++rt) {
            bf16x8 a = *(const bf16x8*)(ao + (16 * rt + l15) * XS_ROW + ks * 32 + g * 8);
            pacc[0][rt] = __builtin_amdgcn_mfma_f32_16x16x32_bf16(a, b0, pacc[0][rt], 0, 0, 0);
            pacc[1][rt] = __builtin_amdgcn_mfma_f32_16x16x32_bf16(a, b1, pacc[1][rt], 0, 0, 0);
        }
    }
    float* outw = out + (size_t)w * (W * D);
    #pragma unroll
    for (int ct = 0; ct < 2; ++ct) {
        const int n = h * 32 + ct * 16 + l15;
        const float bp = bproj[n];
        #pragma unroll
        for (int rt = 0; rt < 4; ++rt)
            #pragma unroll
            for (int r = 0; r < 4; ++r)
                outw[(16 * rt + 4 * g + r) * D + n] = pacc[ct][rt][r] + bp;
    }
}

// Transpose + bf16-convert the weight matrices into workspace (L2-resident).
__global__ void prep_weights(const float* __restrict__ wqkv, const float* __restrict__ wproj,
                             u16* __restrict__ wqkvT, u16* __restrict__ wprojT)
{
    int i = blockIdx.x * 256 + threadIdx.x;
    if (i < 768 * 256) {
        int n = i >> 8, kk = i & 255;
        wqkvT[i] = f2bf(wqkv[kk * 768 + n]);
    } else {
        int j = i - 768 * 256;
        int n = j >> 8, kk = j & 255;
        wprojT[j] = f2bf(wproj[kk * 256 + n]);
    }
}

extern "C" void kernel_launch(void* const* d_in, const int* in_sizes, int n_in,
                              void* d_out, int out_size, void* d_ws, size_t ws_size,
                              hipStream_t stream)
{
    const float* x     = (const float*)d_in[0];
    const float* wqkv  = (const float*)d_in[1];
    const float* bqkv  = (const float*)d_in[2];
    const float* wproj = (const float*)d_in[3];
    const float* bproj = (const float*)d_in[4];
    const float* relb  = (const float*)d_in[5];

    u16* wqkvT  = (u16*)d_ws;                 // 768*256 u16
    u16* wprojT = wqkvT + 768 * 256;          // 256*256 u16

    prep_weights<<<1024, 256, 0, stream>>>(wqkv, wproj, wqkvT, wprojT);

    const int nwin = in_sizes[0] / (W * D);   // 4096
    win_attn9<<<nwin, 512, 0, stream>>>(x, bqkv, bproj, relb, wqkvT, wprojT, (float*)d_out);
}

// Round 13
// 370.745 us; speedup vs baseline: 1.2990x; 1.2990x over previous
//
#include <hip/hip_runtime.h>

#define W 64
#define D 256
#define NH 8

typedef unsigned short u16;
typedef __attribute__((ext_vector_type(8))) short bf16x8;
typedef __attribute__((ext_vector_type(4))) float f32x4;

__device__ __forceinline__ u16 f2bf(float f) {
    union { float f; unsigned u; } v; v.f = f;
    unsigned r = v.u + 0x7fffu + ((v.u >> 16) & 1u);
    return (u16)(r >> 16);
}

// ---------------- LDS layout (bytes) ----------------
// xs   : [64][264] u16   x bf16 staging; dead after QKV; aliased by attn_out 33792
// buf  : per-wave [16][72] u16 transposer (q/k 2-pass, v 2-pass, P)           2304 x 8
// bias : [8][128] f32 rel-pos bias table                                      4096
// total 56320 -> 2 blocks/CU (register-capped anyway; R10 analysis)
// Ordering: all transposer hazards are wave-private LDS. Compiler inserts
// counted lgkmcnt for RAW (proven correct by R9 fence-free run); WAR is safe
// (per-wave DS in order). sched_barrier(0) pins the schedule exactly where
// R10's full drains sat, so regalloc (and thus no-spill) matches R10.
#define XS_ROW 264
#define BUF_ROW 72
#define OFF_BUF 33792
#define OFF_BIAS 52224

#define SBAR() __builtin_amdgcn_sched_barrier(0)

__global__ __launch_bounds__(512, 4) void win_attn10(
    const float* __restrict__ x, const float* __restrict__ bqkv,
    const float* __restrict__ bproj, const float* __restrict__ relb,
    const u16* __restrict__ wqkvT, const u16* __restrict__ wprojT,
    float* __restrict__ out)
{
    __shared__ __align__(16) char smem[56320];

    const int tid  = threadIdx.x;
    const int lane = tid & 63;
    const int h    = tid >> 6;      // wave index == head
    const int l15  = lane & 15;
    const int g    = lane >> 4;
    const int w    = blockIdx.x;

    u16*   xs      = (u16*)smem;
    u16*   buf     = (u16*)(smem + OFF_BUF) + h * 16 * BUF_ROW;
    float* bias_ld = (float*)(smem + OFF_BIAS);

    const f32x4 z4 = {0.f, 0.f, 0.f, 0.f};

    // ---------- Phase 0: bias table + stage x window -> LDS bf16 ----------
    for (int i = tid; i < NH * 127; i += 512)
        bias_ld[(i / 127) * 128 + (i % 127)] = relb[i];

    const float* xw = x + (size_t)w * (W * D);
    #pragma unroll
    for (int i = 0; i < 8; ++i) {
        int e = i * 2048 + tid * 4;
        int row = e >> 8, col = e & 255;
        float4 v = *(const float4*)(xw + e);
        ushort4 b;
        b.x = f2bf(v.x); b.y = f2bf(v.y); b.z = f2bf(v.z); b.w = f2bf(v.w);
        *(ushort4*)(xs + row * XS_ROW + col) = b;
    }
    __syncthreads();

    // ---------- Phase 1: QKV for head h; fragments kept in registers ----------
    bf16x8 qf[4], kf[4], vf[2][2];

    #pragma unroll
    for (int mat = 0; mat < 3; ++mat) {
        f32x4 acc[2][4];
        #pragma unroll
        for (int ct = 0; ct < 2; ++ct)
            #pragma unroll
            for (int rt = 0; rt < 4; ++rt)
                acc[ct][rt] = z4;

        const u16* bp0 = wqkvT + (size_t)(mat * 256 + h * 32 + l15) * 256;
        const u16* bp1 = bp0 + 16 * 256;
        __builtin_amdgcn_s_setprio(1);
        #pragma unroll
        for (int ks = 0; ks < 8; ++ks) {
            bf16x8 b0 = *(const bf16x8*)(bp0 + ks * 32 + g * 8);
            bf16x8 b1 = *(const bf16x8*)(bp1 + ks * 32 + g * 8);
            #pragma unroll
            for (int rt = 0; rt < 4; ++rt) {
                bf16x8 a = *(const bf16x8*)(xs + (16 * rt + l15) * XS_ROW + ks * 32 + g * 8);
                acc[0][rt] = __builtin_amdgcn_mfma_f32_16x16x32_bf16(a, b0, acc[0][rt], 0, 0, 0);
                acc[1][rt] = __builtin_amdgcn_mfma_f32_16x16x32_bf16(a, b1, acc[1][rt], 0, 0, 0);
            }
        }
        __builtin_amdgcn_s_setprio(0);
        const float bias0 = bqkv[mat * 256 + h * 32 + l15];
        const float bias1 = bqkv[mat * 256 + h * 32 + 16 + l15];

        SBAR();
        if (mat < 2) {
            // C-layout (lane=d col, row=4g+r) -> A-frag layout, 2 row-tiles per pass
            #pragma unroll
            for (int rp = 0; rp < 2; ++rp) {
                #pragma unroll
                for (int ct = 0; ct < 2; ++ct) {
                    const float bias = ct ? bias1 : bias0;
                    #pragma unroll
                    for (int rtl = 0; rtl < 2; ++rtl)
                        #pragma unroll
                        for (int r = 0; r < 4; ++r)
                            buf[(4 * g + r) * BUF_ROW + rtl * 32 + ct * 16 + l15] =
                                f2bf(acc[ct][2 * rp + rtl][r] + bias);
                }
                SBAR();
                #pragma unroll
                for (int rtl = 0; rtl < 2; ++rtl) {
                    bf16x8 fr = *(const bf16x8*)(buf + l15 * BUF_ROW + rtl * 32 + g * 8);
                    if (mat == 0) qf[2 * rp + rtl] = fr; else kf[2 * rp + rtl] = fr;
                }
                SBAR();
            }
        } else {
            // v transposed: one cd (16 d-cols) per pass; token index packed b64
            #pragma unroll
            for (int cd = 0; cd < 2; ++cd) {
                const float bias = cd ? bias1 : bias0;
                #pragma unroll
                for (int rt = 0; rt < 4; ++rt) {
                    ushort4 pk;
                    pk.x = f2bf(acc[cd][rt][0] + bias);
                    pk.y = f2bf(acc[cd][rt][1] + bias);
                    pk.z = f2bf(acc[cd][rt][2] + bias);
                    pk.w = f2bf(acc[cd][rt][3] + bias);
                    *(ushort4*)(buf + l15 * BUF_ROW + 16 * rt + 4 * g) = pk;
                }
                SBAR();
                #pragma unroll
                for (int ks = 0; ks < 2; ++ks)
                    vf[ks][cd] = *(const bf16x8*)(buf + l15 * BUF_ROW + ks * 32 + g * 8);
                SBAR();
            }
        }
    }
    __syncthreads();   // all xs reads done -> ao may alias xs

    // ---------- Phase 2: attention (wave-private; P via buf; bias via LDS) ----------
    const float* b2 = bias_ld + h * 128;
    const float scale = 0.17677669529663687f;   // 1/sqrt(32)
    u16* ao = xs;

    #pragma unroll
    for (int rt = 0; rt < 4; ++rt) {
        f32x4 s[4];
        #pragma unroll
        for (int ct = 0; ct < 4; ++ct)
            s[ct] = __builtin_amdgcn_mfma_f32_16x16x32_bf16(qf[rt], kf[ct], z4, 0, 0, 0);

        SBAR();
        float psum[4] = {0.f, 0.f, 0.f, 0.f};
        #pragma unroll
        for (int ct = 0; ct < 4; ++ct) {
            const int ktok = 16 * ct + l15;
            #pragma unroll
            for (int r = 0; r < 4; ++r) {
                const int qtok = 16 * rt + 4 * g + r;
                float sv = s[ct][r] * scale + b2[ktok - qtok + 63];
                float ee = __expf(sv);
                psum[r] += ee;
                buf[(4 * g + r) * BUF_ROW + ct * 16 + l15] = f2bf(ee);
            }
        }
        float inv[4];
        #pragma unroll
        for (int r = 0; r < 4; ++r) {
            float sum = psum[r];
            #pragma unroll
            for (int m = 1; m <= 8; m <<= 1)
                sum += __shfl_xor(sum, m, 64);
            inv[r] = 1.0f / sum;
        }
        SBAR();
        bf16x8 pf0 = *(const bf16x8*)(buf + l15 * BUF_ROW + g * 8);
        bf16x8 pf1 = *(const bf16x8*)(buf + l15 * BUF_ROW + 32 + g * 8);
        #pragma unroll
        for (int cd = 0; cd < 2; ++cd) {
            f32x4 o = __builtin_amdgcn_mfma_f32_16x16x32_bf16(pf0, vf[0][cd], z4, 0, 0, 0);
            o = __builtin_amdgcn_mfma_f32_16x16x32_bf16(pf1, vf[1][cd], o, 0, 0, 0);
            #pragma unroll
            for (int r = 0; r < 4; ++r)
                ao[(16 * rt + 4 * g + r) * XS_ROW + h * 32 + cd * 16 + l15] = f2bf(o[r] * inv[r]);
        }
        SBAR();
    }
    __syncthreads();   // ao complete (cross-wave input to proj)

    // ---------- Phase 3: output projection (wave h -> cols h*32..+31) ----------
    f32x4 pacc[2][4];
    #pragma unroll
    for (int ct = 0; ct < 2; ++ct)
        #pragma unroll
        for (int rt = 0; rt < 4; ++rt)
            pacc[ct][rt] = z4;

    const u16* pp0 = wprojT + (size_t)(h * 32 + l15) * 256;
    const u16* pp1 = pp0 + 16 * 256;
    __builtin_amdgcn_s_setprio(1);
    #pragma unroll
    for (int ks = 0; ks < 8; ++ks) {
        bf16x8 b0 = *(const bf16x8*)(pp0 + ks * 32 + g * 8);
        bf16x8 b1 = *(const bf16x8*)(pp1 + ks * 32 + g * 8);
        #pragma unroll
        for (int rt = 0; rt < 4; ++rt) {
            bf16x8 a = *(const bf16x8*)(ao + (16 * rt + l15) * XS_ROW + ks * 32 + g * 8);
            pacc[0][rt] = __builtin_amdgcn_mfma_f32_16x16x32_bf16(a, b0, pacc[0][rt], 0, 0, 0);
            pacc[1][rt] = __builtin_amdgcn_mfma_f32_16x16x32_bf16(a, b1, pacc[1][rt], 0, 0, 0);
        }
    }
    __builtin_amdgcn_s_setprio(0);

    float* outw = out + (size_t)w * (W * D);
    #pragma unroll
    for (int ct = 0; ct < 2; ++ct) {
        const int n = h * 32 + ct * 16 + l15;
        const float bp = bproj[n];
        #pragma unroll
        for (int rt = 0; rt < 4; ++rt)
            #pragma unroll
            for (int r = 0; r < 4; ++r)
                outw[(16 * rt + 4 * g + r) * D + n] = pacc[ct][rt][r] + bp;
    }
}

// Transpose + bf16-convert the weight matrices into workspace (L2-resident).
__global__ void prep_weights(const float* __restrict__ wqkv, const float* __restrict__ wproj,
                             u16* __restrict__ wqkvT, u16* __restrict__ wprojT)
{
    int i = blockIdx.x * 256 + threadIdx.x;
    if (i < 768 * 256) {
        int n = i >> 8, kk = i & 255;
        wqkvT[i] = f2bf(wqkv[kk * 768 + n]);
    } else {
        int j = i - 768 * 256;
        int n = j >> 8, kk = j & 255;
        wprojT[j] = f2bf(wproj[kk * 256 + n]);
    }
}

extern "C" void kernel_launch(void* const* d_in, const int* in_sizes, int n_in,
                              void* d_out, int out_size, void* d_ws, size_t ws_size,
                              hipStream_t stream)
{
    const float* x     = (const float*)d_in[0];
    const float* wqkv  = (const float*)d_in[1];
    const float* bqkv  = (const float*)d_in[2];
    const float* wproj = (const float*)d_in[3];
    const float* bproj = (const float*)d_in[4];
    const float* relb  = (const float*)d_in[5];

    u16* wqkvT  = (u16*)d_ws;                 // 768*256 u16
    u16* wprojT = wqkvT + 768 * 256;          // 256*256 u16

    prep_weights<<<1024, 256, 0, stream>>>(wqkv, wproj, wqkvT, wprojT);

    const int nwin = in_sizes[0] / (W * D);   // 4096
    win_attn10<<<nwin, 512, 0, stream>>>(x, bqkv, bproj, relb, wqkvT, wprojT, (float*)d_out);
}